// Round 6
// baseline (6277.718 us; speedup 1.0000x reference)
//
#include <hip/hip_runtime.h>
#include <stdint.h>

// ---------------- types / helpers ----------------
typedef short bf16x8 __attribute__((ext_vector_type(8)));
typedef float f32x4  __attribute__((ext_vector_type(4)));

__device__ static inline unsigned short f2bf(float v){
  unsigned x = __float_as_uint(v);
  unsigned r = (x + 0x7fffu + ((x >> 16) & 1u)) >> 16;
  return (unsigned short)r;
}

#define GLOAD16(g, l) \
  __builtin_amdgcn_global_load_lds((const __attribute__((address_space(1))) void*)(g), \
                                   (__attribute__((address_space(3))) void*)(l), 16, 0, 0)

__device__ static inline f32x4 mfma16(bf16x8 a, bf16x8 b, f32x4 c){
  return __builtin_amdgcn_mfma_f32_16x16x32_bf16(a, b, c, 0, 0, 0);
}

// ---------------- prep: weight bf16 round + gate-interleave reorder ----------------
// dst row r = 4*u + g  <-  src row g*1024 + u   (g: 0=i,1=f,2=g,3=o)
__global__ void k_prep_w(const float* __restrict__ Whh0,
                         const float* __restrict__ Wih1, const float* __restrict__ Whh1,
                         unsigned short* __restrict__ W0, unsigned short* __restrict__ W1)
{
  const long n0 = (long)4096 * 1024;
  const long n1 = (long)4096 * 2048;
  long stride = (long)gridDim.x * blockDim.x;
  for (long idx = (long)blockIdx.x * blockDim.x + threadIdx.x; idx < n0 + n1; idx += stride){
    if (idx < n0){
      int i = (int)idx;
      int r = i >> 10, k = i & 1023;
      int u = r >> 2, g = r & 3;
      W0[i] = f2bf(Whh0[(size_t)(g * 1024 + u) * 1024 + k]);
    } else {
      long i = idx - n0;
      int r = (int)(i >> 11), k = (int)(i & 2047);
      int u = r >> 2, g = r & 3;
      int srow = g * 1024 + u;
      float v = (k < 1024) ? Wih1[(size_t)srow * 1024 + k]
                           : Whh1[(size_t)srow * 1024 + (k - 1024)];
      W1[i] = f2bf(v);
    }
  }
}

// ---------------- prep: xw (rank-2 x-proj factors + b0), b1r, zero XA, init out, zero bar ----
__global__ void k_prep_misc(const float* __restrict__ Wih0,
                            const float* __restrict__ bih0, const float* __restrict__ bhh0,
                            const float* __restrict__ bih1, const float* __restrict__ bhh1,
                            const float* __restrict__ bfc,
                            float4* __restrict__ xw, float* __restrict__ b1r,
                            unsigned short* __restrict__ XA,
                            float* __restrict__ out, unsigned* __restrict__ bar)
{
  const long NXA = (long)2 * 512 * 2048;
  const long NO  = (long)512 * 106 * 2;
  const long total = 4096 + 4096 + NXA + NO + 2;
  long stride = (long)gridDim.x * blockDim.x;
  for (long idx = (long)blockIdx.x * blockDim.x + threadIdx.x; idx < total; idx += stride){
    long t = idx;
    if (t < 4096){
      int r = (int)t; int u = r >> 2, g = r & 3; int row = g * 1024 + u;
      xw[r] = make_float4(Wih0[row * 2 + 0], Wih0[row * 2 + 1], bih0[row] + bhh0[row], 0.f);
      continue;
    }
    t -= 4096;
    if (t < 4096){
      int c = (int)t; int u = c >> 2, g = c & 3; int row = g * 1024 + u;
      b1r[c] = bih1[row] + bhh1[row]; continue;
    }
    t -= 4096;
    if (t < NXA){ XA[t] = 0; continue; } t -= NXA;
    if (t < NO){ out[t] = bfc[t & 1]; continue; } t -= NO;
    bar[t] = 0u;
  }
}

// ---------------- device-scope grid barrier (gen-based) ----------------
__device__ static inline void grid_barrier(unsigned* bar, unsigned nb, int tid){
  __syncthreads();                       // also drains vmcnt/lgkmcnt per wave
  if (tid == 0){
    __threadfence();                     // release: L2 writeback, device visibility
    unsigned g = __hip_atomic_load(bar + 1, __ATOMIC_RELAXED, __HIP_MEMORY_SCOPE_AGENT);
    unsigned a = __hip_atomic_fetch_add(bar, 1u, __ATOMIC_ACQ_REL, __HIP_MEMORY_SCOPE_AGENT);
    if (a == nb - 1u){
      __hip_atomic_store(bar, 0u, __ATOMIC_RELAXED, __HIP_MEMORY_SCOPE_AGENT);
      __hip_atomic_fetch_add(bar + 1, 1u, __ATOMIC_RELEASE, __HIP_MEMORY_SCOPE_AGENT);
    } else {
      while (__hip_atomic_load(bar + 1, __ATOMIC_RELAXED, __HIP_MEMORY_SCOPE_AGENT) == g){
        __builtin_amdgcn_s_sleep(1);
      }
    }
    __threadfence();                     // acquire: invalidate L1/L2 for fresh reads
  }
  __syncthreads();
}

// ---------------- persistent fused 2-layer LSTM kernel ----------------
// Per block: fixed (mtile, ntile): BM=64 batch rows x BN=128 gate rows (32 units).
// Per step: phase A (K=1024, NS=16) -> h0 ; barrier ; phase B (K=2048, NS=32) -> h1 + FC ; barrier.
// c-state lives in registers. Epilogue constants preloaded (zero global loads per step).
// GEMM core identical to the verified round-5 kernel (swizzle, 4-stage/3-ahead, counted vmcnt).
__global__ __launch_bounds__(512, 2) void k_persist(
  const unsigned short* __restrict__ W0, const unsigned short* __restrict__ W1,
  const float4* __restrict__ xw, const float* __restrict__ b1r,
  const float* __restrict__ x,
  unsigned short* __restrict__ XA,         // [2][512][2048] bf16
  const float* __restrict__ Wfc, float* __restrict__ out,
  unsigned* __restrict__ bar)
{
  __shared__ char lds[98304];              // 4 stages x 24KB (A 8K | B 16K); forces 1 block/CU
  const int tid = threadIdx.x;
  const int wid = tid >> 6, lane = tid & 63;

  // XCD-grouped mapping: 32 blocks per XCD = 4 N-tiles x 8 M-tiles (grid 256, bijective)
  int L = blockIdx.x;
  int xc = L & 7, j = L >> 3;
  int ntile = xc * 4 + (j & 3);
  int mtile = j >> 2;
  int m0 = mtile * 64, n0 = ntile * 128;
  int wm = wid >> 2, wn = wid & 3;

  // ---- staging segments (wave owns 3 x 1KB of each 24KB stage) ----
  int rsub  = lane >> 3;
  int col16 = (lane & 7) ^ rsub;           // pre-swizzled 16B-chunk column (involution)
  bool sIsA[3]; int segByte[3], segOff0[3], segOff1[3];
  #pragma unroll
  for (int i = 0; i < 3; i++){
    int sg = wid * 3 + i;
    if (sg < 8){
      sIsA[i] = true;
      int row = sg * 8 + rsub;
      segByte[i] = sg * 1024;
      segOff0[i] = (m0 + row) * 2048 + col16 * 8;   // XA row stride 2048 both phases
      segOff1[i] = segOff0[i];
    } else {
      sIsA[i] = false;
      int row = (sg - 8) * 8 + rsub;
      segByte[i] = 8192 + (sg - 8) * 1024;
      segOff0[i] = (n0 + row) * 1024 + col16 * 8;   // W0 row stride 1024
      segOff1[i] = (n0 + row) * 2048 + col16 * 8;   // W1 row stride 2048
    }
  }

  // ---- compute-side swizzled fragment offsets ----
  int offA[2][2], offB[2][2];
  #pragma unroll
  for (int f = 0; f < 2; f++)
    #pragma unroll
    for (int ks = 0; ks < 2; ks++){
      int rowA = wm * 32 + f * 16 + (lane & 15);
      int rowB = wn * 32 + f * 16 + (lane & 15);
      int kb   = ks * 64 + ((lane >> 4) << 4);
      offA[f][ks] = (rowA * 128 + kb) ^ ((rowA & 7) << 4);
      offB[f][ks] = (rowB * 128 + kb) ^ ((rowB & 7) << 4);
    }

  // ---- epilogue constants (fixed per thread across all steps) ----
  const int u  = tid & 31;                 // unit within tile
  const int gu = (n0 >> 2) + u;            // global unit
  float4 xwv[4]; float b1v[4];
  #pragma unroll
  for (int g = 0; g < 4; g++){ xwv[g] = xw[gu * 4 + g]; b1v[g] = b1r[gu * 4 + g]; }
  const float wf0 = Wfc[gu], wf1 = Wfc[1024 + gu];
  int gm_[4]; float2 xv[4];
  #pragma unroll
  for (int it = 0; it < 4; it++){
    gm_[it] = m0 + (it << 4) + (tid >> 5);
    xv[it] = *(const float2*)&x[gm_[it] * 2];
  }
  float c0r[4] = {0.f,0.f,0.f,0.f}, c1r[4] = {0.f,0.f,0.f,0.f};
  float* gl = (float*)lds;

  auto GEMM = [&](const unsigned short* Ab, const unsigned short* Wb,
                  const int* segOff, int NS){
    const unsigned short* gp[3];
    #pragma unroll
    for (int i = 0; i < 3; i++) gp[i] = (sIsA[i] ? Ab : Wb) + segOff[i];
    f32x4 acc[2][2];
    #pragma unroll
    for (int a = 0; a < 2; a++)
      #pragma unroll
      for (int b = 0; b < 2; b++)
        acc[a][b] = (f32x4){0.f, 0.f, 0.f, 0.f};
    auto STG = [&](int sbuf){
      char* ldsb = lds + sbuf * 24576;
      #pragma unroll
      for (int i = 0; i < 3; i++){ GLOAD16(gp[i], ldsb + segByte[i]); gp[i] += 64; }
    };
    STG(0); STG(1); STG(2);
    int cur = 0;
    for (int s = 0; s < NS; s++){
      if (s + 3 < NS){
        STG((cur + 3) & 3);
        asm volatile("s_waitcnt vmcnt(9)" ::: "memory");
      } else if (s + 2 < NS){
        asm volatile("s_waitcnt vmcnt(6)" ::: "memory");
      } else if (s + 1 < NS){
        asm volatile("s_waitcnt vmcnt(3)" ::: "memory");
      } else {
        asm volatile("s_waitcnt vmcnt(0)" ::: "memory");
      }
      __builtin_amdgcn_s_barrier();
      asm volatile("" ::: "memory");
      const char* bb = lds + cur * 24576;
      #pragma unroll
      for (int ks = 0; ks < 2; ks++){
        bf16x8 ah0 = *(const bf16x8*)(bb +        offA[0][ks]);
        bf16x8 ah1 = *(const bf16x8*)(bb +        offA[1][ks]);
        bf16x8 bh0 = *(const bf16x8*)(bb + 8192 + offB[0][ks]);
        bf16x8 bh1 = *(const bf16x8*)(bb + 8192 + offB[1][ks]);
        acc[0][0] = mfma16(ah0, bh0, acc[0][0]);
        acc[0][1] = mfma16(ah0, bh1, acc[0][1]);
        acc[1][0] = mfma16(ah1, bh0, acc[1][0]);
        acc[1][1] = mfma16(ah1, bh1, acc[1][1]);
      }
      asm volatile("" ::: "memory");
      __builtin_amdgcn_s_barrier();
      cur = (cur + 1) & 3;
    }
    // acc -> LDS gates [64][129]
    #pragma unroll
    for (int fm = 0; fm < 2; fm++)
      #pragma unroll
      for (int fn = 0; fn < 2; fn++)
        #pragma unroll
        for (int r = 0; r < 4; r++){
          int row = wm * 32 + fm * 16 + ((lane >> 4) << 2) + r;
          int col = wn * 32 + fn * 16 + (lane & 15);
          gl[row * 129 + col] = acc[fm][fn][r];
        }
    __syncthreads();
  };

  const size_t PS = (size_t)512 * 2048;
  const unsigned NB = gridDim.x;

  for (int t = 0; t < 106; t++){
    int p = t & 1;

    // ---- phase A: layer 0 ----
    GEMM(XA + (size_t)(p ^ 1) * PS, W0, segOff0, 16);
    {
      unsigned short* HA = XA + (size_t)p * PS;
      #pragma unroll
      for (int it = 0; it < 4; it++){
        const float* grow = gl + ((it << 4) + (tid >> 5)) * 129 + (u << 2);
        float gi = grow[0] + xv[it].x * xwv[0].x + xv[it].y * xwv[0].y + xwv[0].z;
        float gf = grow[1] + xv[it].x * xwv[1].x + xv[it].y * xwv[1].y + xwv[1].z;
        float gg = grow[2] + xv[it].x * xwv[2].x + xv[it].y * xwv[2].y + xwv[2].z;
        float go = grow[3] + xv[it].x * xwv[3].x + xv[it].y * xwv[3].y + xwv[3].z;
        float ii = 1.f / (1.f + expf(-gi));
        float ff = 1.f / (1.f + expf(-gf));
        float g2 = tanhf(gg);
        float oo = 1.f / (1.f + expf(-go));
        float c = ff * c0r[it] + ii * g2; c0r[it] = c;
        float h = oo * tanhf(c);
        HA[((size_t)gm_[it] << 11) + gu] = f2bf(h);
      }
    }
    grid_barrier(bar, NB, tid);

    // ---- phase B: layer 1 + FC ----
    GEMM(XA + (size_t)p * PS, W1, segOff1, 32);
    {
      unsigned short* HB = XA + (size_t)(p ^ 1) * PS + 1024;
      #pragma unroll
      for (int it = 0; it < 4; it++){
        const float* grow = gl + ((it << 4) + (tid >> 5)) * 129 + (u << 2);
        float gi = grow[0] + b1v[0];
        float gf = grow[1] + b1v[1];
        float gg = grow[2] + b1v[2];
        float go = grow[3] + b1v[3];
        float ii = 1.f / (1.f + expf(-gi));
        float ff = 1.f / (1.f + expf(-gf));
        float g2 = tanhf(gg);
        float oo = 1.f / (1.f + expf(-go));
        float c = ff * c1r[it] + ii * g2; c1r[it] = c;
        float h = oo * tanhf(c);
        HB[((size_t)gm_[it] << 11) + gu] = f2bf(h);
        float p0 = h * wf0;
        float p1 = h * wf1;
        #pragma unroll
        for (int mm = 16; mm >= 1; mm >>= 1){
          p0 += __shfl_xor(p0, mm);
          p1 += __shfl_xor(p1, mm);
        }
        if ((lane & 31) == 0){
          float* op = out + ((size_t)gm_[it] * 106 + t) * 2;
          atomicAdd(op,     p0);
          atomicAdd(op + 1, p1);
        }
      }
    }
    if (t < 105) grid_barrier(bar, NB, tid);
  }
}

// ---------------- launch ----------------
extern "C" void kernel_launch(void* const* d_in, const int* in_sizes, int n_in,
                              void* d_out, int out_size, void* d_ws, size_t ws_size,
                              hipStream_t stream)
{
  (void)in_sizes; (void)n_in; (void)out_size; (void)ws_size;
  const float* x    = (const float*)d_in[0];
  const float* Wih0 = (const float*)d_in[1];
  const float* Whh0 = (const float*)d_in[2];
  const float* bih0 = (const float*)d_in[3];
  const float* bhh0 = (const float*)d_in[4];
  const float* Wih1 = (const float*)d_in[5];
  const float* Whh1 = (const float*)d_in[6];
  const float* bih1 = (const float*)d_in[7];
  const float* bhh1 = (const float*)d_in[8];
  const float* Wfc  = (const float*)d_in[9];
  const float* bfc  = (const float*)d_in[10];
  float* out = (float*)d_out;

  char* ws = (char*)d_ws;
  size_t off = 0;
  auto carve = [&](size_t bytes)->char*{
    char* p = ws + off;
    off += (bytes + 255) & ~(size_t)255;
    return p;
  };
  unsigned short* W0  = (unsigned short*)carve((size_t)4096 * 1024 * 2);
  unsigned short* W1  = (unsigned short*)carve((size_t)4096 * 2048 * 2);
  float4*         xw  = (float4*)carve((size_t)4096 * 16);
  float*          b1r = (float*)carve((size_t)4096 * 4);
  unsigned short* XA  = (unsigned short*)carve((size_t)2 * 512 * 2048 * 2);
  unsigned*       bar = (unsigned*)carve(256);

  k_prep_w<<<dim3(2048), dim3(256), 0, stream>>>(Whh0, Wih1, Whh1, W0, W1);
  k_prep_misc<<<dim3(2048), dim3(256), 0, stream>>>(Wih0, bih0, bhh0, bih1, bhh1, bfc,
                                                    xw, b1r, XA, out, bar);
  k_persist<<<dim3(256), dim3(512), 0, stream>>>(W0, W1, xw, b1r, x, XA, Wfc, out, bar);
}

// Round 7
// 3589.004 us; speedup vs baseline: 1.7492x; 1.7492x over previous
//
#include <hip/hip_runtime.h>
#include <stdint.h>

// ---------------- types / helpers ----------------
typedef short bf16x8 __attribute__((ext_vector_type(8)));
typedef float f32x4  __attribute__((ext_vector_type(4)));

__device__ static inline unsigned short f2bf(float v){
  unsigned x = __float_as_uint(v);
  unsigned r = (x + 0x7fffu + ((x >> 16) & 1u)) >> 16;
  return (unsigned short)r;
}

#define GLOAD16(g, l) \
  __builtin_amdgcn_global_load_lds((const __attribute__((address_space(1))) void*)(g), \
                                   (__attribute__((address_space(3))) void*)(l), 16, 0, 0)

__device__ static inline f32x4 mfma16(bf16x8 a, bf16x8 b, f32x4 c){
  return __builtin_amdgcn_mfma_f32_16x16x32_bf16(a, b, c, 0, 0, 0);
}

// ---------------- prep: weight bf16 round + gate-interleave reorder ----------------
// dst row r = 4*u + g  <-  src row g*1024 + u   (g: 0=i,1=f,2=g,3=o)
__global__ void k_prep_w(const float* __restrict__ Whh0,
                         const float* __restrict__ Wih1, const float* __restrict__ Whh1,
                         unsigned short* __restrict__ W0hi, unsigned short* __restrict__ W1hi)
{
  const long n0 = (long)4096 * 1024;
  const long n1 = (long)4096 * 2048;
  long stride = (long)gridDim.x * blockDim.x;
  for (long idx = (long)blockIdx.x * blockDim.x + threadIdx.x; idx < n0 + n1; idx += stride){
    if (idx < n0){
      int i = (int)idx;
      int r = i >> 10, k = i & 1023;
      int u = r >> 2, g = r & 3;
      W0hi[i] = f2bf(Whh0[(size_t)(g * 1024 + u) * 1024 + k]);
    } else {
      long i = idx - n0;
      int r = (int)(i >> 11), k = (int)(i & 2047);
      int u = r >> 2, g = r & 3;
      int srow = g * 1024 + u;
      float v = (k < 1024) ? Wih1[(size_t)srow * 1024 + k]
                           : Whh1[(size_t)srow * 1024 + (k - 1024)];
      W1hi[i] = f2bf(v);
    }
  }
}

// ---------------- prep: x-proj+bias (reordered), b1r, zero states, init out ----------------
__global__ void k_prep_misc(const float* __restrict__ x, const float* __restrict__ Wih0,
                            const float* __restrict__ bih0, const float* __restrict__ bhh0,
                            const float* __restrict__ bih1, const float* __restrict__ bhh1,
                            const float* __restrict__ bfc,
                            float* __restrict__ xb0, float* __restrict__ b1r,
                            unsigned short* __restrict__ XAhi,
                            float* __restrict__ c0, float* __restrict__ c1,
                            float* __restrict__ out)
{
  const long NXB = (long)512 * 4096;          // xb0
  const long NXA = (long)2 * 512 * 2048;      // XA (2 parities)
  const long NC  = (long)512 * 1024;
  const long NO  = (long)512 * 106 * 2;
  const long total = NXB + 4096 + NXA + 2 * NC + NO;
  long stride = (long)gridDim.x * blockDim.x;
  for (long idx = (long)blockIdx.x * blockDim.x + threadIdx.x; idx < total; idx += stride){
    long t = idx;
    if (t < NXB){
      int m = (int)(t >> 12), c = (int)(t & 4095);
      int u = c >> 2, g = c & 3;
      int row = g * 1024 + u;
      xb0[t] = x[m * 2 + 0] * Wih0[row * 2 + 0] + x[m * 2 + 1] * Wih0[row * 2 + 1]
             + bih0[row] + bhh0[row];
      continue;
    }
    t -= NXB;
    if (t < 4096){
      int c = (int)t; int u = c >> 2, g = c & 3; int row = g * 1024 + u;
      b1r[c] = bih1[row] + bhh1[row]; continue;
    }
    t -= 4096;
    if (t < NXA){ XAhi[t] = 0; continue; } t -= NXA;
    if (t < NC){ c0[t] = 0.f; continue; } t -= NC;
    if (t < NC){ c1[t] = 0.f; continue; } t -= NC;
    out[t] = bfc[t & 1];
  }
}

// ---------------- fused step kernel: bf16 GEMM + LSTM pointwise (+FC) ----------------
// gates[m, 4u+g] = sum_k A[m,k]*W[4u+g,k] ; A and W both single bf16 (1 MFMA product).
// Tile BM=64, BN=128, BK=64; 8 waves (2x4), wave tile 32x32; grid 256 = 1 block/CU.
// 6-stage LDS ring (24KB/stage: A 8K|B 16K), 5-ahead prefetch, counted vmcnt
// (deepened from 4/3-ahead: cover ~1500cy vs HBM/L3-miss latency ~900cy).
// A rows live in XA [512][2048] bf16, row stride 2048 elements.
__global__ __launch_bounds__(512, 2) void k_lstm_step(
  const unsigned short* __restrict__ Ahi,
  const unsigned short* __restrict__ Whi,
  const float* __restrict__ addv, int addIsMat,
  float* __restrict__ cbuf,
  unsigned short* __restrict__ Hhi_out,
  const float* __restrict__ Wfc, float* __restrict__ pred, int tstep,
  int Kw, int NS)
{
  __shared__ char lds[147456];   // 6 stage buffers x 24KB
  const int tid = threadIdx.x;
  const int wid = tid >> 6, lane = tid & 63;

  // XCD-grouped mapping: 32 blocks per XCD = 4 N-tiles x 8 M-tiles (grid 256, bijective)
  int L = blockIdx.x;
  int xc = L & 7, j = L >> 3;
  int ntile = xc * 4 + (j & 3);
  int mtile = j >> 2;
  int m0 = mtile * 64, n0 = ntile * 128;
  int wm = wid >> 2, wn = wid & 3;

  // ---- staging state (hoisted): wave owns 3 x 1KB segments of the 24KB stage ----
  // segment sg: [0,8)=A row-octet sg, [8,24)=B (weight rows n0..n0+127)
  int rsub  = lane >> 3;                    // row within 8-row octet
  int col16 = (lane & 7) ^ rsub;            // pre-swizzled 16B-chunk column (involution)
  const unsigned short* gp[3];              // per-segment global pointers, advance 64/step
  int segByte[3];                           // wave-uniform LDS byte offset within stage
  #pragma unroll
  for (int i = 0; i < 3; i++){
    int sg = wid * 3 + i;
    int tb, local;
    const unsigned short* base;
    bool isA;
    if (sg < 8) { tb = 0;    local = sg;     base = Ahi; isA = true;  }
    else        { tb = 8192; local = sg - 8; base = Whi; isA = false; }
    int row = local * 8 + rsub;
    gp[i] = isA ? (base + (size_t)(m0 + row) * 2048 + col16 * 8)
                : (base + (size_t)(n0 + row) * Kw   + col16 * 8);
    segByte[i] = tb + local * 1024;
  }

  // ---- compute-side swizzled fragment offsets (stage-invariant) ----
  int offA[2][2], offB[2][2];
  #pragma unroll
  for (int f = 0; f < 2; f++)
    #pragma unroll
    for (int ks = 0; ks < 2; ks++){
      int rowA = wm * 32 + f * 16 + (lane & 15);
      int rowB = wn * 32 + f * 16 + (lane & 15);
      int kb   = ks * 64 + ((lane >> 4) << 4);
      offA[f][ks] = (rowA * 128 + kb) ^ ((rowA & 7) << 4);
      offB[f][ks] = (rowB * 128 + kb) ^ ((rowB & 7) << 4);
    }

  f32x4 acc[2][2];
  #pragma unroll
  for (int a = 0; a < 2; a++)
    #pragma unroll
    for (int b = 0; b < 2; b++)
      acc[a][b] = (f32x4){0.f, 0.f, 0.f, 0.f};

  auto STAGE = [&](int sbuf){
    char* ldsb = lds + sbuf * 24576;
    #pragma unroll
    for (int i = 0; i < 3; i++){
      GLOAD16(gp[i], ldsb + segByte[i]);
      gp[i] += 64;
    }
  };

  STAGE(0); STAGE(1); STAGE(2); STAGE(3); STAGE(4);
  int cur = 0;
  for (int s = 0; s < NS; s++){
    if (s + 5 < NS){
      int nxt = cur + 5; if (nxt >= 6) nxt -= 6;
      STAGE(nxt);
      asm volatile("s_waitcnt vmcnt(15)" ::: "memory");  // stage s landed; s+1..s+5 in flight
    } else if (s + 4 < NS){
      asm volatile("s_waitcnt vmcnt(12)" ::: "memory");
    } else if (s + 3 < NS){
      asm volatile("s_waitcnt vmcnt(9)" ::: "memory");
    } else if (s + 2 < NS){
      asm volatile("s_waitcnt vmcnt(6)" ::: "memory");
    } else if (s + 1 < NS){
      asm volatile("s_waitcnt vmcnt(3)" ::: "memory");
    } else {
      asm volatile("s_waitcnt vmcnt(0)" ::: "memory");
    }
    __builtin_amdgcn_s_barrier();
    asm volatile("" ::: "memory");

    const char* bb = lds + cur * 24576;
    #pragma unroll
    for (int ks = 0; ks < 2; ks++){
      bf16x8 ah0 = *(const bf16x8*)(bb +        offA[0][ks]);
      bf16x8 ah1 = *(const bf16x8*)(bb +        offA[1][ks]);
      bf16x8 bh0 = *(const bf16x8*)(bb + 8192 + offB[0][ks]);
      bf16x8 bh1 = *(const bf16x8*)(bb + 8192 + offB[1][ks]);
      acc[0][0] = mfma16(ah0, bh0, acc[0][0]);
      acc[0][1] = mfma16(ah0, bh1, acc[0][1]);
      acc[1][0] = mfma16(ah1, bh0, acc[1][0]);
      acc[1][1] = mfma16(ah1, bh1, acc[1][1]);
    }
    asm volatile("" ::: "memory");
    __builtin_amdgcn_s_barrier();
    cur += 1; if (cur >= 6) cur -= 6;
  }

  // ---------- epilogue: acc -> LDS gates [64][129], then pointwise LSTM ----------
  float* gl = (float*)lds;
  #pragma unroll
  for (int fm = 0; fm < 2; fm++)
    #pragma unroll
    for (int fn = 0; fn < 2; fn++)
      #pragma unroll
      for (int r = 0; r < 4; r++){
        int row = wm * 32 + fm * 16 + ((lane >> 4) << 2) + r;   // batch row in tile
        int col = wn * 32 + fn * 16 + (lane & 15);              // gate col in tile
        gl[row * 129 + col] = acc[fm][fn][r];
      }
  __syncthreads();

  #pragma unroll
  for (int it = 0; it < 4; it++){
    int u    = tid & 31;                 // unit 0..31 within tile
    int rowl = (it << 4) + (tid >> 5);   // batch row 0..63 within tile
    int gm = m0 + rowl;
    int gu = (n0 >> 2) + u;              // global unit 0..1023
    const float* grow = gl + rowl * 129 + (u << 2);
    float gi = grow[0], gf = grow[1], gg = grow[2], go = grow[3];
    if (addIsMat){
      const float* a = addv + ((size_t)gm << 12) + n0 + (u << 2);
      gi += a[0]; gf += a[1]; gg += a[2]; go += a[3];
    } else {
      const float* a = addv + n0 + (u << 2);
      gi += a[0]; gf += a[1]; gg += a[2]; go += a[3];
    }
    float ii = 1.f / (1.f + expf(-gi));
    float ff = 1.f / (1.f + expf(-gf));
    float g2 = tanhf(gg);
    float oo = 1.f / (1.f + expf(-go));
    size_t ci = ((size_t)gm << 10) + gu;
    float c = ff * cbuf[ci] + ii * g2;
    cbuf[ci] = c;
    float h = oo * tanhf(c);
    size_t hi_idx = ((size_t)gm << 11) + gu;   // XA row stride 2048 (base pre-offset per layer)
    Hhi_out[hi_idx] = f2bf(h);
    if (pred){
      float p0 = h * Wfc[gu];
      float p1 = h * Wfc[1024 + gu];
      #pragma unroll
      for (int mm = 16; mm >= 1; mm >>= 1){
        p0 += __shfl_xor(p0, mm);
        p1 += __shfl_xor(p1, mm);
      }
      if ((lane & 31) == 0){
        float* op = pred + ((size_t)gm * 106 + tstep) * 2;
        atomicAdd(op,     p0);
        atomicAdd(op + 1, p1);
      }
    }
  }
}

// ---------------- launch ----------------
extern "C" void kernel_launch(void* const* d_in, const int* in_sizes, int n_in,
                              void* d_out, int out_size, void* d_ws, size_t ws_size,
                              hipStream_t stream)
{
  (void)in_sizes; (void)n_in; (void)out_size; (void)ws_size;
  const float* x    = (const float*)d_in[0];
  const float* Wih0 = (const float*)d_in[1];
  const float* Whh0 = (const float*)d_in[2];
  const float* bih0 = (const float*)d_in[3];
  const float* bhh0 = (const float*)d_in[4];
  const float* Wih1 = (const float*)d_in[5];
  const float* Whh1 = (const float*)d_in[6];
  const float* bih1 = (const float*)d_in[7];
  const float* bhh1 = (const float*)d_in[8];
  const float* Wfc  = (const float*)d_in[9];
  const float* bfc  = (const float*)d_in[10];
  float* out = (float*)d_out;

  char* ws = (char*)d_ws;
  size_t off = 0;
  auto carve = [&](size_t bytes)->char*{
    char* p = ws + off;
    off += (bytes + 255) & ~(size_t)255;
    return p;
  };
  unsigned short* W0hi = (unsigned short*)carve((size_t)4096 * 1024 * 2);
  unsigned short* W1hi = (unsigned short*)carve((size_t)4096 * 2048 * 2);
  float*          xb0  = (float*)carve((size_t)512 * 4096 * 4);
  float*          b1r  = (float*)carve((size_t)4096 * 4);
  unsigned short* XAhi = (unsigned short*)carve((size_t)2 * 512 * 2048 * 2);
  float*          c0   = (float*)carve((size_t)512 * 1024 * 4);
  float*          c1   = (float*)carve((size_t)512 * 1024 * 4);

  k_prep_w<<<dim3(2048), dim3(256), 0, stream>>>(Whh0, Wih1, Whh1, W0hi, W1hi);
  k_prep_misc<<<dim3(2048), dim3(256), 0, stream>>>(x, Wih0, bih0, bhh0, bih1, bhh1, bfc,
                                                    xb0, b1r, XAhi, c0, c1, out);

  const int PS = 512 * 2048;   // parity stride (elements) of XA
  for (int t = 0; t < 106; t++){
    int p = t & 1;
    // layer 0: gates = h0(t-1) @ W0^T + xb0 ; A = XA[p^1] cols 0..1023 ; K=1024, NS=16
    k_lstm_step<<<dim3(256), dim3(512), 0, stream>>>(
      XAhi + (p ^ 1) * PS,
      W0hi, xb0, 1, c0,
      XAhi + p * PS,                                // h0(t) -> XA[p] cols 0..1023
      (const float*)nullptr, (float*)nullptr, t, 1024, 16);
    // layer 1: gates = [h0(t)|h1(t-1)] @ W1^T + b1 ; A = XA[p] ; K=2048, NS=32 ; + FC
    k_lstm_step<<<dim3(256), dim3(512), 0, stream>>>(
      XAhi + p * PS,
      W1hi, b1r, 0, c1,
      XAhi + (p ^ 1) * PS + 1024,                   // h1(t) -> XA[p^1] cols 1024..
      Wfc, out, t, 2048, 32);
  }
}

// Round 8
// 3402.601 us; speedup vs baseline: 1.8450x; 1.0548x over previous
//
#include <hip/hip_runtime.h>
#include <stdint.h>

// ---------------- types / helpers ----------------
typedef short bf16x8 __attribute__((ext_vector_type(8)));
typedef float f32x4  __attribute__((ext_vector_type(4)));

__device__ static inline unsigned short f2bf(float v){
  unsigned x = __float_as_uint(v);
  unsigned r = (x + 0x7fffu + ((x >> 16) & 1u)) >> 16;
  return (unsigned short)r;
}

#define GLOAD16(g, l) \
  __builtin_amdgcn_global_load_lds((const __attribute__((address_space(1))) void*)(g), \
                                   (__attribute__((address_space(3))) void*)(l), 16, 0, 0)

__device__ static inline f32x4 mfma16(bf16x8 a, bf16x8 b, f32x4 c){
  return __builtin_amdgcn_mfma_f32_16x16x32_bf16(a, b, c, 0, 0, 0);
}

// ---------------- prep: weight bf16 round + gate-interleave reorder ----------------
// dst row r = 4*u + g  <-  src row g*1024 + u   (g: 0=i,1=f,2=g,3=o)
__global__ void k_prep_w(const float* __restrict__ Whh0,
                         const float* __restrict__ Wih1, const float* __restrict__ Whh1,
                         unsigned short* __restrict__ W0hi, unsigned short* __restrict__ W1hi)
{
  const long n0 = (long)4096 * 1024;
  const long n1 = (long)4096 * 2048;
  long stride = (long)gridDim.x * blockDim.x;
  for (long idx = (long)blockIdx.x * blockDim.x + threadIdx.x; idx < n0 + n1; idx += stride){
    if (idx < n0){
      int i = (int)idx;
      int r = i >> 10, k = i & 1023;
      int u = r >> 2, g = r & 3;
      W0hi[i] = f2bf(Whh0[(size_t)(g * 1024 + u) * 1024 + k]);
    } else {
      long i = idx - n0;
      int r = (int)(i >> 11), k = (int)(i & 2047);
      int u = r >> 2, g = r & 3;
      int srow = g * 1024 + u;
      float v = (k < 1024) ? Wih1[(size_t)srow * 1024 + k]
                           : Whh1[(size_t)srow * 1024 + (k - 1024)];
      W1hi[i] = f2bf(v);
    }
  }
}

// ---------------- prep: x-proj+bias (reordered), b1r, zero states, init out ----------------
__global__ void k_prep_misc(const float* __restrict__ x, const float* __restrict__ Wih0,
                            const float* __restrict__ bih0, const float* __restrict__ bhh0,
                            const float* __restrict__ bih1, const float* __restrict__ bhh1,
                            const float* __restrict__ bfc,
                            float* __restrict__ xb0, float* __restrict__ b1r,
                            unsigned short* __restrict__ XAhi,
                            float* __restrict__ c0, float* __restrict__ c1,
                            float* __restrict__ out)
{
  const long NXB = (long)512 * 4096;          // xb0
  const long NXA = (long)2 * 512 * 2048;      // XA (2 parities)
  const long NC  = (long)512 * 1024;
  const long NO  = (long)512 * 106 * 2;
  const long total = NXB + 4096 + NXA + 2 * NC + NO;
  long stride = (long)gridDim.x * blockDim.x;
  for (long idx = (long)blockIdx.x * blockDim.x + threadIdx.x; idx < total; idx += stride){
    long t = idx;
    if (t < NXB){
      int m = (int)(t >> 12), c = (int)(t & 4095);
      int u = c >> 2, g = c & 3;
      int row = g * 1024 + u;
      xb0[t] = x[m * 2 + 0] * Wih0[row * 2 + 0] + x[m * 2 + 1] * Wih0[row * 2 + 1]
             + bih0[row] + bhh0[row];
      continue;
    }
    t -= NXB;
    if (t < 4096){
      int c = (int)t; int u = c >> 2, g = c & 3; int row = g * 1024 + u;
      b1r[c] = bih1[row] + bhh1[row]; continue;
    }
    t -= 4096;
    if (t < NXA){ XAhi[t] = 0; continue; } t -= NXA;
    if (t < NC){ c0[t] = 0.f; continue; } t -= NC;
    if (t < NC){ c1[t] = 0.f; continue; } t -= NC;
    out[t] = bfc[t & 1];
  }
}

// ---------------- fused step kernel: bf16 GEMM + LSTM pointwise (+FC) ----------------
// gates[m, 4u+g] = sum_k A[m,k]*W[4u+g,k] ; A and W both single bf16 (1 MFMA product).
// Tile BM=64, BN=128, BK=64; 8 waves (2x4), wave tile 32x32; grid 256 = 1 block/CU.
// 6-stage LDS ring (24KB/stage: A 8K|B 16K); TWO K-steps per barrier phase
// (halves barrier count; 32 MFMA + 16 ds_read schedulable per phase), counted vmcnt.
// A rows live in XA [512][2048] bf16, row stride 2048 elements.
__global__ __launch_bounds__(512, 2) void k_lstm_step(
  const unsigned short* __restrict__ Ahi,
  const unsigned short* __restrict__ Whi,
  const float* __restrict__ addv, int addIsMat,
  float* __restrict__ cbuf,
  unsigned short* __restrict__ Hhi_out,
  const float* __restrict__ Wfc, float* __restrict__ pred, int tstep,
  int Kw, int NS)
{
  __shared__ char lds[147456];   // 6 stage buffers x 24KB
  const int tid = threadIdx.x;
  const int wid = tid >> 6, lane = tid & 63;

  // XCD-grouped mapping: 32 blocks per XCD = 4 N-tiles x 8 M-tiles (grid 256, bijective)
  int L = blockIdx.x;
  int xc = L & 7, j = L >> 3;
  int ntile = xc * 4 + (j & 3);
  int mtile = j >> 2;
  int m0 = mtile * 64, n0 = ntile * 128;
  int wm = wid >> 2, wn = wid & 3;

  // ---- staging state (hoisted): wave owns 3 x 1KB segments of the 24KB stage ----
  // segment sg: [0,8)=A row-octet sg, [8,24)=B (weight rows n0..n0+127)
  int rsub  = lane >> 3;                    // row within 8-row octet
  int col16 = (lane & 7) ^ rsub;            // pre-swizzled 16B-chunk column (involution)
  const unsigned short* gp[3];              // per-segment global pointers, advance 64/step
  int segByte[3];                           // wave-uniform LDS byte offset within stage
  #pragma unroll
  for (int i = 0; i < 3; i++){
    int sg = wid * 3 + i;
    int tb, local;
    const unsigned short* base;
    bool isA;
    if (sg < 8) { tb = 0;    local = sg;     base = Ahi; isA = true;  }
    else        { tb = 8192; local = sg - 8; base = Whi; isA = false; }
    int row = local * 8 + rsub;
    gp[i] = isA ? (base + (size_t)(m0 + row) * 2048 + col16 * 8)
                : (base + (size_t)(n0 + row) * Kw   + col16 * 8);
    segByte[i] = tb + local * 1024;
  }

  // ---- compute-side swizzled fragment offsets (stage-invariant) ----
  int offA[2][2], offB[2][2];
  #pragma unroll
  for (int f = 0; f < 2; f++)
    #pragma unroll
    for (int ks = 0; ks < 2; ks++){
      int rowA = wm * 32 + f * 16 + (lane & 15);
      int rowB = wn * 32 + f * 16 + (lane & 15);
      int kb   = ks * 64 + ((lane >> 4) << 4);
      offA[f][ks] = (rowA * 128 + kb) ^ ((rowA & 7) << 4);
      offB[f][ks] = (rowB * 128 + kb) ^ ((rowB & 7) << 4);
    }

  f32x4 acc[2][2];
  #pragma unroll
  for (int a = 0; a < 2; a++)
    #pragma unroll
    for (int b = 0; b < 2; b++)
      acc[a][b] = (f32x4){0.f, 0.f, 0.f, 0.f};

  auto STAGE = [&](int sbuf){
    char* ldsb = lds + sbuf * 24576;
    #pragma unroll
    for (int i = 0; i < 3; i++){
      GLOAD16(gp[i], ldsb + segByte[i]);
      gp[i] += 64;
    }
  };

  // prologue: 4 stages in flight (12 loads/wave)
  STAGE(0); STAGE(1); STAGE(2); STAGE(3);
  int base = 0;
  const int NP = NS >> 1;                  // 2 K-steps per phase
  for (int p = 0; p < NP; p++){
    if (p + 2 < NP){
      int n4 = base + 4; if (n4 >= 6) n4 -= 6;
      int n5 = base + 5; if (n5 >= 6) n5 -= 6;
      STAGE(n4); STAGE(n5);
      asm volatile("s_waitcnt vmcnt(12)" ::: "memory");  // phase stages landed; 4 in flight
    } else if (p + 1 < NP){
      asm volatile("s_waitcnt vmcnt(6)" ::: "memory");
    } else {
      asm volatile("s_waitcnt vmcnt(0)" ::: "memory");
    }
    __builtin_amdgcn_s_barrier();
    asm volatile("" ::: "memory");

    int b1i = base + 1; if (b1i >= 6) b1i -= 6;
    const char* bbs[2] = { lds + base * 24576, lds + b1i * 24576 };
    #pragma unroll
    for (int half = 0; half < 2; half++){
      const char* bb = bbs[half];
      #pragma unroll
      for (int ks = 0; ks < 2; ks++){
        bf16x8 ah0 = *(const bf16x8*)(bb +        offA[0][ks]);
        bf16x8 ah1 = *(const bf16x8*)(bb +        offA[1][ks]);
        bf16x8 bh0 = *(const bf16x8*)(bb + 8192 + offB[0][ks]);
        bf16x8 bh1 = *(const bf16x8*)(bb + 8192 + offB[1][ks]);
        acc[0][0] = mfma16(ah0, bh0, acc[0][0]);
        acc[0][1] = mfma16(ah0, bh1, acc[0][1]);
        acc[1][0] = mfma16(ah1, bh0, acc[1][0]);
        acc[1][1] = mfma16(ah1, bh1, acc[1][1]);
      }
    }
    asm volatile("" ::: "memory");
    __builtin_amdgcn_s_barrier();
    base += 2; if (base >= 6) base -= 6;
  }

  // ---------- epilogue: acc -> LDS gates [64][129], then pointwise LSTM ----------
  float* gl = (float*)lds;
  #pragma unroll
  for (int fm = 0; fm < 2; fm++)
    #pragma unroll
    for (int fn = 0; fn < 2; fn++)
      #pragma unroll
      for (int r = 0; r < 4; r++){
        int row = wm * 32 + fm * 16 + ((lane >> 4) << 2) + r;   // batch row in tile
        int col = wn * 32 + fn * 16 + (lane & 15);              // gate col in tile
        gl[row * 129 + col] = acc[fm][fn][r];
      }
  __syncthreads();

  #pragma unroll
  for (int it = 0; it < 4; it++){
    int u    = tid & 31;                 // unit 0..31 within tile
    int rowl = (it << 4) + (tid >> 5);   // batch row 0..63 within tile
    int gm = m0 + rowl;
    int gu = (n0 >> 2) + u;              // global unit 0..1023
    const float* grow = gl + rowl * 129 + (u << 2);
    float gi = grow[0], gf = grow[1], gg = grow[2], go = grow[3];
    if (addIsMat){
      const float* a = addv + ((size_t)gm << 12) + n0 + (u << 2);
      gi += a[0]; gf += a[1]; gg += a[2]; go += a[3];
    } else {
      const float* a = addv + n0 + (u << 2);
      gi += a[0]; gf += a[1]; gg += a[2]; go += a[3];
    }
    float ii = 1.f / (1.f + expf(-gi));
    float ff = 1.f / (1.f + expf(-gf));
    float g2 = tanhf(gg);
    float oo = 1.f / (1.f + expf(-go));
    size_t ci = ((size_t)gm << 10) + gu;
    float c = ff * cbuf[ci] + ii * g2;
    cbuf[ci] = c;
    float h = oo * tanhf(c);
    size_t hi_idx = ((size_t)gm << 11) + gu;   // XA row stride 2048 (base pre-offset per layer)
    Hhi_out[hi_idx] = f2bf(h);
    if (pred){
      float p0 = h * Wfc[gu];
      float p1 = h * Wfc[1024 + gu];
      #pragma unroll
      for (int mm = 16; mm >= 1; mm >>= 1){
        p0 += __shfl_xor(p0, mm);
        p1 += __shfl_xor(p1, mm);
      }
      if ((lane & 31) == 0){
        float* op = pred + ((size_t)gm * 106 + tstep) * 2;
        atomicAdd(op,     p0);
        atomicAdd(op + 1, p1);
      }
    }
  }
}

// ---------------- launch ----------------
extern "C" void kernel_launch(void* const* d_in, const int* in_sizes, int n_in,
                              void* d_out, int out_size, void* d_ws, size_t ws_size,
                              hipStream_t stream)
{
  (void)in_sizes; (void)n_in; (void)out_size; (void)ws_size;
  const float* x    = (const float*)d_in[0];
  const float* Wih0 = (const float*)d_in[1];
  const float* Whh0 = (const float*)d_in[2];
  const float* bih0 = (const float*)d_in[3];
  const float* bhh0 = (const float*)d_in[4];
  const float* Wih1 = (const float*)d_in[5];
  const float* Whh1 = (const float*)d_in[6];
  const float* bih1 = (const float*)d_in[7];
  const float* bhh1 = (const float*)d_in[8];
  const float* Wfc  = (const float*)d_in[9];
  const float* bfc  = (const float*)d_in[10];
  float* out = (float*)d_out;

  char* ws = (char*)d_ws;
  size_t off = 0;
  auto carve = [&](size_t bytes)->char*{
    char* p = ws + off;
    off += (bytes + 255) & ~(size_t)255;
    return p;
  };
  unsigned short* W0hi = (unsigned short*)carve((size_t)4096 * 1024 * 2);
  unsigned short* W1hi = (unsigned short*)carve((size_t)4096 * 2048 * 2);
  float*          xb0  = (float*)carve((size_t)512 * 4096 * 4);
  float*          b1r  = (float*)carve((size_t)4096 * 4);
  unsigned short* XAhi = (unsigned short*)carve((size_t)2 * 512 * 2048 * 2);
  float*          c0   = (float*)carve((size_t)512 * 1024 * 4);
  float*          c1   = (float*)carve((size_t)512 * 1024 * 4);

  k_prep_w<<<dim3(2048), dim3(256), 0, stream>>>(Whh0, Wih1, Whh1, W0hi, W1hi);
  k_prep_misc<<<dim3(2048), dim3(256), 0, stream>>>(x, Wih0, bih0, bhh0, bih1, bhh1, bfc,
                                                    xb0, b1r, XAhi, c0, c1, out);

  const int PS = 512 * 2048;   // parity stride (elements) of XA
  for (int t = 0; t < 106; t++){
    int p = t & 1;
    // layer 0: gates = h0(t-1) @ W0^T + xb0 ; A = XA[p^1] cols 0..1023 ; K=1024, NS=16
    k_lstm_step<<<dim3(256), dim3(512), 0, stream>>>(
      XAhi + (p ^ 1) * PS,
      W0hi, xb0, 1, c0,
      XAhi + p * PS,                                // h0(t) -> XA[p] cols 0..1023
      (const float*)nullptr, (float*)nullptr, t, 1024, 16);
    // layer 1: gates = [h0(t)|h1(t-1)] @ W1^T + b1 ; A = XA[p] ; K=2048, NS=32 ; + FC
    k_lstm_step<<<dim3(256), dim3(512), 0, stream>>>(
      XAhi + p * PS,
      W1hi, b1r, 0, c1,
      XAhi + (p ^ 1) * PS + 1024,                   // h1(t) -> XA[p^1] cols 1024..
      Wfc, out, t, 2048, 32);
  }
}